// Round 2
// baseline (242.552 us; speedup 1.0000x reference)
//
#include <hip/hip_runtime.h>

// B=64, S=512, D=768 fp32.
// out = concat( hidden[:,0,:] (64*768), segment-mean by sent_id (64*20*768) )
// Grid (64 batches, 4 col-chunks of 192 floats) = 256 blocks = 1/CU.
// Block (64 lanes, 16 row-groups) = 1024 threads = 16 waves.
// Each lane loads float3 (dwordx3): 64*12B = 768B contiguous per wave-inst.
// 8-deep register prefetch ring keeps ~6KB/wave (96KB/CU) in flight.

constexpr int B_ = 64;
constexpr int S_ = 512;
constexpr int D_ = 768;
constexpr int M1 = 21;   // segments accumulated (sid in [0,20])
constexpr int MS = 20;   // segments emitted
constexpr int CF = 192;  // floats per column chunk (64 lanes x 3)
constexpr int G  = 16;   // waves per block
constexpr int ROWS = S_ / G;  // 32 rows per wave
constexpr int P  = 8;    // prefetch depth

struct f3 { float x, y, z; };

__global__ __launch_bounds__(64 * G, 4)
void aspire_kernel(const float* __restrict__ hidden,
                   const int* __restrict__ sent_ids,
                   float* __restrict__ out) {
    __shared__ float acc[M1 * CF];   // 16128 B
    __shared__ int   sids[S_];       // 2048 B
    __shared__ int   cnt[M1];

    const int b    = blockIdx.x;
    const int dc   = blockIdx.y;
    const int lane = threadIdx.x;    // 0..63
    const int g    = threadIdx.y;    // 0..15
    const int tid  = g * 64 + lane;

    // init LDS
    for (int i = tid; i < M1 * CF; i += 64 * G) acc[i] = 0.0f;
    if (tid < M1) cnt[tid] = 0;
    __syncthreads();

    // stage sent_ids + per-(b,seg) counts
    if (tid < S_) {
        int sv = sent_ids[b * S_ + tid];
        sids[tid] = sv;
        atomicAdd(&cnt[sv], 1);
    }
    __syncthreads();

    const float* hp = hidden + (size_t)b * S_ * D_ + dc * CF + 3 * lane;

    // doc_cls_reps = hidden[:,0,:]
    if (tid < CF) {
        out[b * D_ + dc * CF + tid] =
            hidden[(size_t)b * S_ * D_ + dc * CF + tid];
    }

    // ---- main loop: wave g handles rows s = t*G + g, t = 0..31 ----
    f3 buf[P];
    #pragma unroll
    for (int j = 0; j < P; ++j) {
        int s = j * G + g;
        buf[j] = *(const f3*)(hp + (size_t)s * D_);
    }

    #pragma unroll 1
    for (int ii = 0; ii < ROWS - P; ii += P) {
        #pragma unroll
        for (int j = 0; j < P; ++j) {
            int s   = (ii + j) * G + g;
            int sid = sids[s];                 // LDS broadcast read
            float* a = &acc[sid * CF + 3 * lane];
            f3 v = buf[j];
            atomicAdd(a + 0, v.x);             // ds_add_f32, 2 lanes/bank = free
            atomicAdd(a + 1, v.y);
            atomicAdd(a + 2, v.z);
            int sn = (ii + j + P) * G + g;     // refill slot j (independent of adds)
            buf[j] = *(const f3*)(hp + (size_t)sn * D_);
        }
    }
    #pragma unroll
    for (int j = 0; j < P; ++j) {
        int s   = (ROWS - P + j) * G + g;
        int sid = sids[s];
        float* a = &acc[sid * CF + 3 * lane];
        f3 v = buf[j];
        atomicAdd(a + 0, v.x);
        atomicAdd(a + 1, v.y);
        atomicAdd(a + 2, v.z);
    }
    __syncthreads();

    // ---- epilogue: sent_reps = acc / max(cnt,1), coalesced ----
    float* srep = out + (size_t)B_ * D_;
    for (int f = tid; f < MS * CF; f += 64 * G) {
        int seg = f / CF;
        int col = f - seg * CF;
        float ct = (float)cnt[seg];
        ct = ct < 1.0f ? 1.0f : ct;
        srep[((size_t)b * MS + seg) * D_ + dc * CF + col] =
            acc[seg * CF + col] / ct;
    }
}

extern "C" void kernel_launch(void* const* d_in, const int* in_sizes, int n_in,
                              void* d_out, int out_size, void* d_ws, size_t ws_size,
                              hipStream_t stream) {
    const float* hidden   = (const float*)d_in[0];
    const int*   sent_ids = (const int*)d_in[1];
    float* out = (float*)d_out;

    dim3 grid(B_, D_ / CF);   // (64, 4) = 256 blocks
    dim3 block(64, G);        // 1024 threads = 16 waves
    aspire_kernel<<<grid, block, 0, stream>>>(hidden, sent_ids, out);
}

// Round 3
// 154.949 us; speedup vs baseline: 1.5654x; 1.5654x over previous
//
#include <hip/hip_runtime.h>

// B=64, S=512, D=768 fp32.
// out = concat( hidden[:,0,:] (64*768), segment-mean by sent_id (64*20*768) )
// Grid (64, 4): block owns one batch x 192-float column chunk. 1024 thr = 16 waves.
// Counting-sort rows by sid (once, int LDS atomics), then each wave does a
// sorted segmented sum over 32 rows in registers (sid wave-uniform -> scalar
// branch at run boundaries), flushing partial sums to LDS rarely.
// 8-deep register prefetch ring; no fp atomics in the straight-line hot path.

constexpr int B_ = 64;
constexpr int S_ = 512;
constexpr int D_ = 768;
constexpr int M1 = 21;    // sid in [0,20]
constexpr int MS = 20;    // segments emitted
constexpr int CF = 192;   // floats per column chunk (64 lanes x 3)
constexpr int G  = 16;    // waves per block
constexpr int RPW = S_ / G;  // 32 sorted positions per wave
constexpr int P  = 8;     // prefetch depth

struct f3 { float x, y, z; };

__global__ __launch_bounds__(64 * G, 1)
void aspire_kernel(const float* __restrict__ hidden,
                   const int* __restrict__ sent_ids,
                   float* __restrict__ out) {
    __shared__ float acc[M1 * CF];    // 16128 B
    __shared__ int   cnt[M1];
    __shared__ int   offs[M1];
    __shared__ short ord[S_];         // row index, sorted by sid
    __shared__ short ssid[S_];        // sid at sorted position
    __shared__ int   sids[S_];

    const int b    = blockIdx.x;
    const int dc   = blockIdx.y;
    const int lane = threadIdx.x;     // 0..63
    const int g    = threadIdx.y;     // 0..15
    const int tid  = g * 64 + lane;

    // ---- init + counting sort (int atomics only; once per block) ----
    for (int i = tid; i < M1 * CF; i += 64 * G) acc[i] = 0.0f;
    if (tid < M1) cnt[tid] = 0;
    __syncthreads();
    if (tid < S_) {
        int sv = sent_ids[b * S_ + tid];
        sids[tid] = sv;
        atomicAdd(&cnt[sv], 1);       // ds_add_u32 (native int RMW)
    }
    __syncthreads();
    if (tid == 0) {
        int r = 0;
        for (int k = 0; k < M1; ++k) { offs[k] = r; r += cnt[k]; }
    }
    __syncthreads();
    if (tid < S_) {
        int sv  = sids[tid];
        int pos = atomicAdd(&offs[sv], 1);
        ord[pos]  = (short)tid;
        ssid[pos] = (short)sv;
    }
    // doc_cls_reps = hidden[:,0,:]
    if (tid < CF) {
        out[b * D_ + dc * CF + tid] = hidden[(size_t)b * S_ * D_ + dc * CF + tid];
    }
    __syncthreads();

    // ---- hot loop: sorted segmented sum, registers only ----
    const float* hb = hidden + (size_t)b * S_ * D_ + dc * CF + 3 * lane;
    const int p0 = g * RPW;

    f3 buf[P];
    #pragma unroll
    for (int j = 0; j < P; ++j) {
        int s = ord[p0 + j];
        buf[j] = *(const f3*)(hb + (size_t)s * D_);
    }

    float sx = 0.0f, sy = 0.0f, sz = 0.0f;
    int cur = ssid[p0];

    #pragma unroll 1
    for (int t0 = 0; t0 < RPW - P; t0 += P) {
        #pragma unroll
        for (int j = 0; j < P; ++j) {
            int t   = t0 + j;
            int sid = ssid[p0 + t];            // wave-uniform LDS read
            if (sid != cur) {                  // scalar branch, rare
                float* a = &acc[cur * CF + 3 * lane];
                atomicAdd(a + 0, sx);
                atomicAdd(a + 1, sy);
                atomicAdd(a + 2, sz);
                sx = sy = sz = 0.0f;
                cur = sid;
            }
            f3 v = buf[j];
            sx += v.x; sy += v.y; sz += v.z;
            int sn = ord[p0 + t + P];          // refill (independent of adds)
            buf[j] = *(const f3*)(hb + (size_t)sn * D_);
        }
    }
    #pragma unroll
    for (int j = 0; j < P; ++j) {              // tail: consume only
        int t   = RPW - P + j;
        int sid = ssid[p0 + t];
        if (sid != cur) {
            float* a = &acc[cur * CF + 3 * lane];
            atomicAdd(a + 0, sx);
            atomicAdd(a + 1, sy);
            atomicAdd(a + 2, sz);
            sx = sy = sz = 0.0f;
            cur = sid;
        }
        f3 v = buf[j];
        sx += v.x; sy += v.y; sz += v.z;
    }
    {   // final flush
        float* a = &acc[cur * CF + 3 * lane];
        atomicAdd(a + 0, sx);
        atomicAdd(a + 1, sy);
        atomicAdd(a + 2, sz);
    }
    __syncthreads();

    // ---- epilogue: sent_reps = acc / max(cnt,1), coalesced ----
    float* srep = out + (size_t)B_ * D_;
    for (int f = tid; f < MS * CF; f += 64 * G) {
        int seg = f / CF;
        int col = f - seg * CF;
        float ct = (float)cnt[seg];
        ct = ct < 1.0f ? 1.0f : ct;
        srep[((size_t)b * MS + seg) * D_ + dc * CF + col] =
            acc[seg * CF + col] / ct;
    }
}

extern "C" void kernel_launch(void* const* d_in, const int* in_sizes, int n_in,
                              void* d_out, int out_size, void* d_ws, size_t ws_size,
                              hipStream_t stream) {
    const float* hidden   = (const float*)d_in[0];
    const int*   sent_ids = (const int*)d_in[1];
    float* out = (float*)d_out;

    dim3 grid(B_, D_ / CF);   // (64, 4) = 256 blocks = 1/CU
    dim3 block(64, G);        // 1024 threads = 16 waves
    aspire_kernel<<<grid, block, 0, stream>>>(hidden, sent_ids, out);
}

// Round 4
// 153.284 us; speedup vs baseline: 1.5824x; 1.0109x over previous
//
#include <hip/hip_runtime.h>

// B=64, S=512, D=768 fp32.
// out = concat( hidden[:,0,:] (64*768), segment-mean by sent_id (64*20*768) )
// Grid (64 batches, 3 col-chunks of 256 floats) = 192 blocks.
// Block (64 lanes, 16 waves) = 1024 threads; wave-load = 64 x float4 = 1 KB.
// Counting-sort rows by sid once (int LDS atomics), then sorted segmented sum
// in registers (sid wave-uniform -> scalar branch), rare LDS flushes.
// 8-deep float4 register prefetch ring = 128 KB in flight per CU.

constexpr int B_ = 64;
constexpr int S_ = 512;
constexpr int D_ = 768;
constexpr int M1 = 21;    // sid in [0,20]
constexpr int MS = 20;    // segments emitted
constexpr int CF = 256;   // floats per column chunk (64 lanes x 4)
constexpr int NC = D_ / CF;  // 3 chunks
constexpr int G  = 16;    // waves per block
constexpr int RPW = S_ / G;  // 32 sorted positions per wave
constexpr int P  = 8;     // prefetch depth

__global__ __launch_bounds__(64 * G, 1)
void aspire_kernel(const float* __restrict__ hidden,
                   const int* __restrict__ sent_ids,
                   float* __restrict__ out) {
    __shared__ float acc[M1 * CF];    // 21504 B
    __shared__ int   cnt[M1];
    __shared__ int   offs[M1];
    __shared__ short ord[S_];         // row index, sorted by sid
    __shared__ short ssid[S_];        // sid at sorted position
    __shared__ int   sids[S_];

    const int b    = blockIdx.x;
    const int dc   = blockIdx.y;
    const int lane = threadIdx.x;     // 0..63
    const int g    = threadIdx.y;     // 0..15
    const int tid  = g * 64 + lane;

    // ---- init + counting sort (int atomics only; once per block) ----
    for (int i = tid; i < M1 * CF; i += 64 * G) acc[i] = 0.0f;
    if (tid < M1) cnt[tid] = 0;
    __syncthreads();
    if (tid < S_) {
        int sv = sent_ids[b * S_ + tid];
        sids[tid] = sv;
        atomicAdd(&cnt[sv], 1);       // ds_add_u32
    }
    __syncthreads();
    if (tid == 0) {
        int r = 0;
        for (int k = 0; k < M1; ++k) { offs[k] = r; r += cnt[k]; }
    }
    __syncthreads();
    if (tid < S_) {
        int sv  = sids[tid];
        int pos = atomicAdd(&offs[sv], 1);
        ord[pos]  = (short)tid;
        ssid[pos] = (short)sv;
    }
    // doc_cls_reps = hidden[:,0,:]
    if (tid < CF) {
        out[b * D_ + dc * CF + tid] = hidden[(size_t)b * S_ * D_ + dc * CF + tid];
    }
    __syncthreads();

    // ---- hot loop: sorted segmented sum, registers only ----
    const float* hb = hidden + (size_t)b * S_ * D_ + dc * CF + 4 * lane;
    const int p0 = g * RPW;

    float4 buf[P];
    #pragma unroll
    for (int j = 0; j < P; ++j) {
        int s = ord[p0 + j];
        buf[j] = *(const float4*)(hb + (size_t)s * D_);
    }

    float sx = 0.0f, sy = 0.0f, sz = 0.0f, sw = 0.0f;
    int cur = ssid[p0];

    #pragma unroll 1
    for (int t0 = 0; t0 < RPW - P; t0 += P) {
        #pragma unroll
        for (int j = 0; j < P; ++j) {
            int t   = t0 + j;
            int sid = ssid[p0 + t];            // wave-uniform LDS read
            if (sid != cur) {                  // scalar branch, rare
                float* a = &acc[cur * CF + 4 * lane];
                atomicAdd(a + 0, sx);
                atomicAdd(a + 1, sy);
                atomicAdd(a + 2, sz);
                atomicAdd(a + 3, sw);
                sx = sy = sz = sw = 0.0f;
                cur = sid;
            }
            float4 v = buf[j];
            sx += v.x; sy += v.y; sz += v.z; sw += v.w;
            int sn = ord[p0 + t + P];          // refill (independent of adds)
            buf[j] = *(const float4*)(hb + (size_t)sn * D_);
        }
    }
    #pragma unroll
    for (int j = 0; j < P; ++j) {              // tail: consume only
        int t   = RPW - P + j;
        int sid = ssid[p0 + t];
        if (sid != cur) {
            float* a = &acc[cur * CF + 4 * lane];
            atomicAdd(a + 0, sx);
            atomicAdd(a + 1, sy);
            atomicAdd(a + 2, sz);
            atomicAdd(a + 3, sw);
            sx = sy = sz = sw = 0.0f;
            cur = sid;
        }
        float4 v = buf[j];
        sx += v.x; sy += v.y; sz += v.z; sw += v.w;
    }
    {   // final flush
        float* a = &acc[cur * CF + 4 * lane];
        atomicAdd(a + 0, sx);
        atomicAdd(a + 1, sy);
        atomicAdd(a + 2, sz);
        atomicAdd(a + 3, sw);
    }
    __syncthreads();

    // ---- epilogue: sent_reps = acc / max(cnt,1), coalesced ----
    float* srep = out + (size_t)B_ * D_;
    for (int f = tid; f < MS * CF; f += 64 * G) {
        int seg = f / CF;
        int col = f - seg * CF;
        float ct = (float)cnt[seg];
        ct = ct < 1.0f ? 1.0f : ct;
        srep[((size_t)b * MS + seg) * D_ + dc * CF + col] =
            acc[seg * CF + col] / ct;
    }
}

extern "C" void kernel_launch(void* const* d_in, const int* in_sizes, int n_in,
                              void* d_out, int out_size, void* d_ws, size_t ws_size,
                              hipStream_t stream) {
    const float* hidden   = (const float*)d_in[0];
    const int*   sent_ids = (const int*)d_in[1];
    float* out = (float*)d_out;

    dim3 grid(B_, NC);        // (64, 3) = 192 blocks
    dim3 block(64, G);        // 1024 threads = 16 waves
    aspire_kernel<<<grid, block, 0, stream>>>(hidden, sent_ids, out);
}